// Round 1
// 200.559 us; speedup vs baseline: 1.0164x; 1.0164x over previous
//
#include <hip/hip_runtime.h>

// GaussianPooling: fm[512,256,256] f32, keypoints[4096,2] int, out[4096,512] f32.
// 5x5 gaussian sigma=2, separable: k = g(dy)*g(dx)/s^2.
//
// R10 (= R9 structure + two changes):
//  - Staging via __builtin_amdgcn_global_load_lds width=16 (LDS-DMA).
//    Each wave stages one full 256-float row: per-lane global addr contiguous
//    (gr*1024 + lane*16 B), LDS dest = wave-uniform base row*1040 + lane*16 B
//    (1040 = 65*16, aligned). Removes the VGPR round-trip + staging VALU
//    (compiler never auto-emits this; +67% on GEMM staging per learn_hip m193).
//  - Single-block bucket kernel (1024 thr, 4 kp/thr): with one block the LDS
//    histogram rank IS the final list position -> no global atomic reservation,
//    no hipMemsetAsync zeroing pass. 3 launches -> 2.
//  - Kept from R9: XCD write-merge swizzle (16 blocks sharing an out-line land
//    on one XCD so dword stores merge into full lines in its L2), 16-row
//    strips (20x260 LDS = 20.8 KB -> 7 blocks/CU, 28 waves/CU, 8192 blocks).

#define NC  512
#define NH  256
#define NW  256
#define NKP 4096

#define NSTRIP 16              // y-strips of 16 rows
#define SLICE_ROWS 20          // 16 + 2x2 halo
#define STR 260                // LDS row stride: +4 keeps 16B align, rotates banks

// ws layout (int32 offsets):
//   [0..16)                    cnt[16]   (written by bucket_kernel, no memset)
//   [8192 .. 8192+16*NKP)      packed lists (i | x<<12 | y<<20), stride NKP
#define WS_LIST_OFF_I 8192

// ---------------- bucket: ONE block, 1024 thr, 4 kp/thr ----------------
// Single block => LDS-atomic rank is the final within-strip position; counts
// are written directly (no zero pass, no cross-block reservation).
__global__ __launch_bounds__(1024) void bucket_kernel(
    const int* __restrict__ kp, unsigned* __restrict__ ws_i, int n_kp)
{
    __shared__ int hist[NSTRIP];
    const int t = threadIdx.x;

    if (t < NSTRIP) hist[t] = 0;
    __syncthreads();

    int      q[4], lr[4];
    unsigned pk[4];
    bool     valid[4];
#pragma unroll
    for (int j = 0; j < 4; ++j) {
        const int i = t + j * 1024;
        valid[j] = (i < n_kp);
        q[j] = 0; lr[j] = 0; pk[j] = 0u;
        if (valid[j]) {
            int x = kp[2 * i + 0];
            int y = kp[2 * i + 1];
            x = min(max(x, 2), NW - 3);
            y = min(max(y, 2), NH - 3);
            q[j]  = y >> 4;
            lr[j] = atomicAdd(&hist[q[j]], 1);
            pk[j] = (unsigned)i | ((unsigned)x << 12) | ((unsigned)y << 20);
        }
    }
    __syncthreads();

    if (t < NSTRIP) ws_i[t] = (unsigned)hist[t];   // final counts

#pragma unroll
    for (int j = 0; j < 4; ++j)
        if (valid[j])
            ws_i[WS_LIST_OFF_I + q[j] * NKP + lr[j]] = pk[j];
}

// ---------------- pool: 1-D grid of 8192, decode (c,q) with XCD swizzle ----------------
__global__ __launch_bounds__(256) void pool_kernel(
    const float* __restrict__ fm, const unsigned* __restrict__ ws_i,
    float* __restrict__ out)
{
    __shared__ float plane[SLICE_ROWS * STR];   // 20,800 B -> 7 blocks/CU

    // decode swizzled block id: b = (chunk&7) + 8*((chunk>>3)*256 + q*16 + lane)
    const int b     = blockIdx.x;
    const int x7    = b & 7;
    const int inner = b >> 3;
    const int hi    = inner >> 8;          // chunk>>3, 0..3
    const int rem   = inner & 255;
    const int q     = rem >> 4;            // 0..15
    const int l16   = rem & 15;
    const int chunk = (hi << 3) | x7;      // 0..31
    const int c     = (chunk << 4) | l16;  // 0..511

    const int t    = threadIdx.x;
    const int w    = t >> 6;               // wave 0..3
    const int lane = t & 63;
    const int ybase = (q << 4) - 2;

    // overlap the scalar cnt load with staging latency
    const int cnt = (int)ws_i[q];

    // stage rows [ybase, ybase+19] clamped to [0,255] via LDS-DMA.
    // wave w, iter it -> row = w + 4*it (wave-uniform guard), 64 lanes x 16 B
    // = one full 1024 B row; LDS dest row*1040 + lane*16 (16B-aligned).
    const float* src = fm + ((size_t)c << 16);
#pragma unroll
    for (int it = 0; it < 5; ++it) {
        const int row = w + (it << 2);
        const int gr  = ybase + row;
        if ((unsigned)gr < 256u) {
            const float* g = src + ((size_t)gr << 8) + (lane << 2);
            float*       l = &plane[row * STR + (lane << 2)];
            __builtin_amdgcn_global_load_lds(
                (const __attribute__((address_space(1))) void*)g,
                (__attribute__((address_space(3))) void*)l,
                16, 0, 0);
        }
    }

    // gaussian weights (VALU work while loads fly, before the barrier)
    const float e1 = 0.8824969025845955f;  // exp(-1/8)
    const float e2 = 0.6065306597126334f;  // exp(-4/8)
    const float s  = 2.0f * (e1 + e2) + 1.0f;
    const float inv_s2 = 1.0f / (s * s);
    const float g[5] = {e2, e1, 1.0f, e1, e2};
    float gy[5];
#pragma unroll
    for (int i = 0; i < 5; i++) gy[i] = g[i] * inv_s2;

    __syncthreads();   // drains vmcnt -> LDS-DMA complete

    const unsigned* list = ws_i + WS_LIST_OFF_I + q * NKP;

    for (int e = t; e < cnt; e += 256) {
        const unsigned pk = list[e];
        const int n  = (int)(pk & 0xFFFu);
        const int xc = (int)((pk >> 12) & 0xFFu);
        const int yc = (int)((pk >> 20) & 0xFFu);

        const int x0 = xc - 2;
        const int r  = x0 & 3;
        const int xa = x0 - r;
        float wx[8];
#pragma unroll
        for (int i = 0; i < 8; i++)
            wx[i] = (i >= r && i < r + 5) ? g[i - r] : 0.0f;

        const int lr0 = yc - (q << 4);     // plane row of (yc-2): 0..15
        float acc = 0.0f;
#pragma unroll
        for (int dy = 0; dy < 5; dy++) {
            const float* rowp = &plane[(lr0 + dy) * STR + xa];
            float4 a  = *(const float4*)rowp;
            float4 b4 = *(const float4*)(rowp + 4);
            acc += gy[dy] * (a.x * wx[0] + a.y * wx[1] + a.z * wx[2] + a.w * wx[3]
                           + b4.x * wx[4] + b4.y * wx[5] + b4.z * wx[6] + b4.w * wx[7]);
        }
        out[(size_t)n * NC + c] = acc;     // dword store; merges in same-XCD L2
    }
}

// ---------------- fallback (round-1 direct kernel) ----------------
__global__ __launch_bounds__(256) void gpool_direct_kernel(
    const float* __restrict__ fm, const int* __restrict__ kp,
    float* __restrict__ out)
{
    const int n = blockIdx.x;
    const int t = threadIdx.x;

    int x = kp[2 * n + 0];
    int y = kp[2 * n + 1];
    x = min(max(x, 2), NW - 3);
    y = min(max(y, 2), NH - 3);

    const float e1 = 0.8824969025845955f;
    const float e2 = 0.6065306597126334f;
    const float s  = 2.0f * (e1 + e2) + 1.0f;
    const float inv_s2 = 1.0f / (s * s);
    float g[5] = {e2, e1, 1.0f, e1, e2};
    float gy[5];
#pragma unroll
    for (int i = 0; i < 5; i++) gy[i] = g[i] * inv_s2;

    const int x0 = x - 2;
    const int r  = x0 & 3;
    const int xa = x0 - r;
    float wx[8];
#pragma unroll
    for (int i = 0; i < 8; i++)
        wx[i] = (i >= r && i < r + 5) ? g[i - r] : 0.0f;

    const float* base0 = fm + ((size_t)t * NH + (y - 2)) * NW + xa;
    const float* base1 = fm + ((size_t)(t + 256) * NH + (y - 2)) * NW + xa;

    float acc0 = 0.0f, acc1 = 0.0f;
#pragma unroll
    for (int dy = 0; dy < 5; dy++) {
        const float4* p0 = (const float4*)(base0 + dy * NW);
        const float4* p1 = (const float4*)(base1 + dy * NW);
        float4 a0 = p0[0], b0 = p0[1], a1 = p1[0], b1 = p1[1];
        acc0 += gy[dy] * (a0.x * wx[0] + a0.y * wx[1] + a0.z * wx[2] + a0.w * wx[3]
                        + b0.x * wx[4] + b0.y * wx[5] + b0.z * wx[6] + b0.w * wx[7]);
        acc1 += gy[dy] * (a1.x * wx[0] + a1.y * wx[1] + a1.z * wx[2] + a1.w * wx[3]
                        + b1.x * wx[4] + b1.y * wx[5] + b1.z * wx[6] + b1.w * wx[7]);
    }

    out[(size_t)n * NC + t]       = acc0;
    out[(size_t)n * NC + t + 256] = acc1;
}

extern "C" void kernel_launch(void* const* d_in, const int* in_sizes, int n_in,
                              void* d_out, int out_size, void* d_ws, size_t ws_size,
                              hipStream_t stream)
{
    const float* fm  = (const float*)d_in[0];
    const int*   kp  = (const int*)d_in[1];
    float*       out = (float*)d_out;
    const int n_kp   = in_sizes[1] / 2;   // 4096

    const size_t need = (WS_LIST_OFF_I + (size_t)NSTRIP * NKP) * sizeof(unsigned);
    if (ws_size >= need && n_kp == NKP) {
        unsigned* ws_i = (unsigned*)d_ws;

        bucket_kernel<<<1, 1024, 0, stream>>>(kp, ws_i, n_kp);

        pool_kernel<<<NC * NSTRIP, 256, 0, stream>>>(fm, ws_i, out);
    } else {
        gpool_direct_kernel<<<n_kp, 256, 0, stream>>>(fm, kp, out);
    }
}